// Round 14
// baseline (5107.475 us; speedup 1.0000x reference)
//
#include <hip/hip_runtime.h>

#define B_SZ 512
#define S_SZ 256
#define D_SZ 512
#define H_SZ 512

typedef __bf16 bf16x8 __attribute__((ext_vector_type(8)));
typedef __bf16 bf16x4 __attribute__((ext_vector_type(4)));
typedef float f32x4 __attribute__((ext_vector_type(4)));
typedef int i32x4 __attribute__((ext_vector_type(4)));
typedef unsigned long long u64;

// ---------------- ws layout (bytes) ----------------
// [0, 32KB)       : step flags: 8 groups x 32 WG-slots x 128B
// [32KB, 64KB)    : xcc flags:  8 groups x 32 WG-slots x 128B
// [64KB, +1MB)    : state parity 0: h0 (512x512 bf16) then cf0 (c*f_att)
// [+1MB, +2MB)    : state parity 1
// [2162688, +4MB) : GwT 4*512*1024 bf16 (g, j, k)
// [6356992, +.5MB): WeT 512*512 bf16 (j, k)
// [6881280, +128MB): x_bf16 (optional, if ws_size permits)
#define FLAGS_BYTES 65536
#define STATE_OFF FLAGS_BYTES
#define STATE_PAR_ELEMS (2 * H_SZ * B_SZ)
#define GWT_OFF_BYTES (STATE_OFF + 2097152)
#define WET_OFF_BYTES (GWT_OFF_BYTES + 4194304)
#define XB_OFF_BYTES (WET_OFF_BYTES + 524288)
#define XB_BYTES ((size_t)B_SZ * S_SZ * D_SZ * 2)

// XOR swizzle: 2-way max bank aliasing on ds_read_b128 (free per m136)
#define SWZ(j, k) ((k) ^ (((j) & 7) << 3) ^ ((((j) >> 3) & 1) << 6))

__device__ __forceinline__ float sigmoidf_(float v) {
    return 1.f / (1.f + __expf(-v));
}
__device__ __forceinline__ float tanhf_(float v) {
    return 1.f - 2.f / (1.f + __expf(2.f * v));
}

// LLC-coherent accesses (fallback + flag protocol): relaxed agent atomics ->
// sc0 sc1 on BOTH store and load sides (same coherence point => live).
// [R12 lesson: never mix sc-scopes across a signal/poll pair.]
__device__ __forceinline__ u64 coh_load(const u64* p) {
    return __hip_atomic_load(p, __ATOMIC_RELAXED, __HIP_MEMORY_SCOPE_AGENT);
}
__device__ __forceinline__ void coh_store(u64* p, u64 v) {
    __hip_atomic_store(p, v, __ATOMIC_RELAXED, __HIP_MEMORY_SCOPE_AGENT);
}

__global__ __launch_bounds__(256) void prep_weights(
    const float* __restrict__ We,
    const float* __restrict__ Ui, const float* __restrict__ Vi,
    const float* __restrict__ Uf, const float* __restrict__ Vf,
    const float* __restrict__ Uc, const float* __restrict__ Vc,
    const float* __restrict__ Uo, const float* __restrict__ Vo,
    __bf16* __restrict__ GwT, __bf16* __restrict__ WeT)
{
    const int bid = blockIdx.x;
    const int tid = threadIdx.x;
    if (bid < 2048) {
        const int g = bid >> 9;
        const int j = bid & 511;
        const float* U = (g == 0) ? Ui : (g == 1) ? Uf : (g == 2) ? Uc : Uo;
        const float* V = (g == 0) ? Vi : (g == 1) ? Vf : (g == 2) ? Vc : Vo;
        __bf16* dst = GwT + ((size_t)(g * 512 + j) << 10);
        for (int k = tid; k < 1024; k += 256) {
            float v = (k < 512) ? U[k * 512 + j] : V[(k - 512) * 512 + j];
            dst[k] = (__bf16)v;
        }
    } else {
        const int j = bid - 2048;
        __bf16* dst = WeT + ((size_t)j << 9);
        for (int k = tid; k < 512; k += 256) {
            dst[k] = (__bf16)We[k * 512 + j];
        }
    }
}

// One-time x f32 -> bf16 (numerics identical to per-step conversion).
__global__ __launch_bounds__(256) void xcvt(const float* __restrict__ x,
                                            __bf16* __restrict__ xb)
{
    const size_t i = ((size_t)blockIdx.x * 256 + threadIdx.x) * 8;
    f32x4 a = *(const f32x4*)(x + i);
    f32x4 b = *(const f32x4*)(x + i + 4);
    bf16x8 o;
    o[0] = (__bf16)a[0]; o[1] = (__bf16)a[1]; o[2] = (__bf16)a[2]; o[3] = (__bf16)a[3];
    o[4] = (__bf16)b[0]; o[5] = (__bf16)b[1]; o[6] = (__bf16)b[2]; o[7] = (__bf16)b[3];
    *(bf16x8*)(xb + i) = o;
}

// Persistent recurrent kernel, K-SPLIT 8-wave version.
// 256 WGs x 512 thr, 1 WG/CU (160KB LDS) -> 2 waves/SIMD.
// WG (rblk=bid&7, cblk=bid>>3): batch rows [rblk*64,+64) x cols [cblk*16,+16).
// Waves 0-3 (X side): x@U partials (K 0..512) for rows wave*16..+16 -> LDS red.
// Waves 4-7 (H side): state loads + h@V + cf@We (K 512..1024) for the same
// rows, then += red, elementwise, publish. Wave i & i+4 share a SIMD ->
// memory-heavy H overlaps MFMA-heavy X (m114 co-scheduling).
// Sync/coherence primitives = round-11/13 PROVEN RECIPE, unchanged.
template <bool XB>
__global__ __launch_bounds__(512, 1) void lstm_persist(
    const float* __restrict__ x, const __bf16* __restrict__ xb,
    const float* __restrict__ tseq,
    const float* __restrict__ b_i, const float* __restrict__ b_f,
    const float* __restrict__ b_c, const float* __restrict__ b_o,
    const float* __restrict__ b_e,
    const __bf16* __restrict__ GwT, const __bf16* __restrict__ WeT,
    __bf16* __restrict__ state, int* __restrict__ flags,
    float* __restrict__ out)
{
    __shared__ __align__(16) __bf16 wlds[4][16][1024];   // 128 KB
    __shared__ __align__(16) __bf16 welds[16][512];      // 16 KB
    __shared__ __align__(16) float red[4][64][16];       // 16 KB -> 160 KiB

    const int tid = threadIdx.x;
    const int bid = blockIdx.x;
    const int rblk = bid & 7;
    const int cblk = bid >> 3;
    const int j0 = cblk << 4;
    const int wave = tid >> 6;       // 0..7
    const int side = wave >> 2;      // 0 = X (x@U), 1 = H (h@V + We + epilogue)
    const int wrow = wave & 3;       // row sub-block
    const int lane = tid & 63;
    const int alr = lane & 15;       // weight row j (A-frag row)
    const int hq = lane >> 4;        // k-subgroup / C j-quad
    const int kbase = hq * 8;

    // ---- stage weights into LDS, swizzled (once; 512 threads) ----
    for (int e = tid * 8; e < 4 * 16 * 1024; e += 512 * 8) {
        const int g = e >> 14;
        const int j = (e >> 10) & 15;
        const int k = e & 1023;
        *(uint4*)&wlds[g][j][SWZ(j, k)] =
            *(const uint4*)&GwT[((size_t)(g * 512 + j0 + j) << 10) + k];
    }
    for (int e = tid * 8; e < 16 * 512; e += 512 * 8) {
        const int j = e >> 9;
        const int k = e & 511;
        *(uint4*)&welds[j][SWZ(j, k)] =
            *(const uint4*)&WeT[((size_t)(j0 + j) << 9) + k];
    }
    __syncthreads();

    const int brow = rblk * 64 + wrow * 16 + alr;   // batch row (this wave-pair)
    const int jbase = j0 + hq * 4;                   // 4 consecutive j (C rows)
    const f32x4 Bi4 = *(const f32x4*)(b_i + jbase);
    const f32x4 Bf4 = *(const f32x4*)(b_f + jbase);
    const f32x4 Bc4 = *(const f32x4*)(b_c + jbase);
    const f32x4 Bo4 = *(const f32x4*)(b_o + jbase);
    const f32x4 Be4 = *(const f32x4*)(b_e + jbase);

    const float* xrow = x + (size_t)brow * S_SZ * D_SZ;
    const __bf16* xrowb = XB ? xb + (size_t)brow * S_SZ * D_SZ : nullptr;
    const float* tsrow = tseq + (size_t)brow * S_SZ;
    const size_t hoff = (size_t)brow * H_SZ;
    float* outrow = out + (size_t)brow * S_SZ * H_SZ + jbase;

    // step-flag slots (128B stride) + per-lane poll pointer
    int* gflags = flags + rblk * 32 * 32;
    int* myflag = gflags + cblk * 32;
    const int* pollp = gflags + (lane & 31) * 32;

    // ---- XCD-locality check (one-time, proven rounds 6/9/10/11/13) ----
    int* xgrp = flags + 8192 + rblk * 32 * 32;
    unsigned xcc;
    asm volatile("s_getreg_b32 %0, hwreg(HW_REG_XCC_ID)" : "=s"(xcc));
    if (tid == 0)
        __hip_atomic_store(xgrp + cblk * 32, (int)xcc + 1,
                           __ATOMIC_RELAXED, __HIP_MEMORY_SCOPE_AGENT);
    int vx;
    const int* xpoll = xgrp + (lane & 31) * 32;
    for (;;) {
        vx = __hip_atomic_load(xpoll, __ATOMIC_RELAXED, __HIP_MEMORY_SCOPE_AGENT);
        if (__all(vx != 0)) break;
        __builtin_amdgcn_s_sleep(1);
    }
    const bool l2ok = __all(vx == __shfl(vx, 0, 64));

    // X-side prologue: x[0] fragments
    bf16x8 xbf[16];
    if (side == 0) {
        if constexpr (XB) {
            #pragma unroll
            for (int kk = 0; kk < 16; ++kk)
                xbf[kk] = *(const bf16x8*)(xrowb + kk * 32 + kbase);
        } else {
            #pragma unroll
            for (int kk = 0; kk < 16; ++kk) {
                f32x4 u = *(const f32x4*)(xrow + kk * 32 + kbase);
                f32x4 v = *(const f32x4*)(xrow + kk * 32 + kbase + 4);
                bf16x8 a;
                a[0] = (__bf16)u[0]; a[1] = (__bf16)u[1]; a[2] = (__bf16)u[2]; a[3] = (__bf16)u[3];
                a[4] = (__bf16)v[0]; a[5] = (__bf16)v[1]; a[6] = (__bf16)v[2]; a[7] = (__bf16)v[3];
                xbf[kk] = a;
            }
        }
    }

    for (int t = 0; t < S_SZ; ++t) {
        const __bf16* hp = state + (size_t)(t & 1) * STATE_PAR_ELEMS;
        const __bf16* cp = hp + (size_t)H_SZ * B_SZ;
        __bf16* hnx = state + (size_t)((t + 1) & 1) * STATE_PAR_ELEMS;
        __bf16* cnx = hnx + (size_t)H_SZ * B_SZ;

        f32x4 a0, a1, a2, a3, a4;
        union HU { i32x4 q; u64 u[2]; bf16x8 v; };
        HU hs[16], cs[16];

        if (side == 0) {
            // ---- X side: x@U partials (no bias) ----
            f32x4 p0 = {0,0,0,0}, p1 = {0,0,0,0}, p2 = {0,0,0,0}, p3 = {0,0,0,0};
            #pragma unroll
            for (int kk = 0; kk < 16; ++kk) {
                const int k = SWZ(alr, kk * 32 + kbase);
                bf16x8 w0 = *(const bf16x8*)&wlds[0][alr][k];
                bf16x8 w1 = *(const bf16x8*)&wlds[1][alr][k];
                bf16x8 w2 = *(const bf16x8*)&wlds[2][alr][k];
                bf16x8 w3 = *(const bf16x8*)&wlds[3][alr][k];
                p0 = __builtin_amdgcn_mfma_f32_16x16x32_bf16(w0, xbf[kk], p0, 0, 0, 0);
                p1 = __builtin_amdgcn_mfma_f32_16x16x32_bf16(w1, xbf[kk], p1, 0, 0, 0);
                p2 = __builtin_amdgcn_mfma_f32_16x16x32_bf16(w2, xbf[kk], p2, 0, 0, 0);
                p3 = __builtin_amdgcn_mfma_f32_16x16x32_bf16(w3, xbf[kk], p3, 0, 0, 0);
            }
            float* rp = &red[wrow][lane][0];
            *(f32x4*)(rp + 0)  = p0;
            *(f32x4*)(rp + 4)  = p1;
            *(f32x4*)(rp + 8)  = p2;
            *(f32x4*)(rp + 12) = p3;
        } else {
            // ---- H side: state loads + h@V + cf@We ----
            if (l2ok) {
                const __bf16* hb = hp + hoff + kbase;
                const __bf16* cb = cp + hoff + kbase;
                #pragma unroll
                for (int kk = 0; kk < 16; ++kk) {
                    hs[kk].q = *(const i32x4*)(hb + kk * 32);
                    cs[kk].q = *(const i32x4*)(cb + kk * 32);
                }
            } else {
                #pragma unroll
                for (int kk = 0; kk < 16; ++kk) {
                    const u64* ph = (const u64*)(hp + hoff + kbase + kk * 32);
                    const u64* pc = (const u64*)(cp + hoff + kbase + kk * 32);
                    hs[kk].u[0] = coh_load(ph);
                    hs[kk].u[1] = coh_load(ph + 1);
                    cs[kk].u[0] = coh_load(pc);
                    cs[kk].u[1] = coh_load(pc + 1);
                }
            }
            a0 = Bi4; a1 = Bf4; a2 = Bc4; a3 = Bo4; a4 = Be4;
            #pragma unroll
            for (int kk = 0; kk < 16; ++kk) {
                const int k = SWZ(alr, 512 + kk * 32 + kbase);
                bf16x8 w0 = *(const bf16x8*)&wlds[0][alr][k];
                bf16x8 w1 = *(const bf16x8*)&wlds[1][alr][k];
                bf16x8 w2 = *(const bf16x8*)&wlds[2][alr][k];
                bf16x8 w3 = *(const bf16x8*)&wlds[3][alr][k];
                bf16x8 we = *(const bf16x8*)&welds[alr][SWZ(alr, kk * 32 + kbase)];
                a0 = __builtin_amdgcn_mfma_f32_16x16x32_bf16(w0, hs[kk].v, a0, 0, 0, 0);
                a1 = __builtin_amdgcn_mfma_f32_16x16x32_bf16(w1, hs[kk].v, a1, 0, 0, 0);
                a2 = __builtin_amdgcn_mfma_f32_16x16x32_bf16(w2, hs[kk].v, a2, 0, 0, 0);
                a3 = __builtin_amdgcn_mfma_f32_16x16x32_bf16(w3, hs[kk].v, a3, 0, 0, 0);
                a4 = __builtin_amdgcn_mfma_f32_16x16x32_bf16(we, cs[kk].v, a4, 0, 0, 0);
            }
        }

        __syncthreads();   // red visible to H side

        if (side == 1) {
            // ---- H side: merge partials, elementwise, publish ----
            const float* rp = &red[wrow][lane][0];
            a0 += *(const f32x4*)(rp + 0);
            a1 += *(const f32x4*)(rp + 4);
            a2 += *(const f32x4*)(rp + 8);
            a3 += *(const f32x4*)(rp + 12);

            const float fa = (t + 1 < S_SZ) ? tsrow[t + 1] : 0.f;
            f32x4 hv4, cv4;
            union { bf16x4 v; u64 u; } ph8, pc8;
            #pragma unroll
            for (int e = 0; e < 4; ++e) {
                float it = sigmoidf_(a0[e]);
                float ft = sigmoidf_(a1[e]);
                float gt = tanhf_(a2[e]);
                float ot = sigmoidf_(a3[e]);
                float ctl = tanhf_(a4[e]);
                float cv = ft * ctl + it * gt;
                float hv = ot * tanhf_(cv);
                hv4[e] = hv; cv4[e] = cv;
                ph8.v[e] = (__bf16)hv;
                pc8.v[e] = (__bf16)(cv * fa);
            }
            __builtin_nontemporal_store(hv4, (f32x4*)(outrow + (size_t)t * H_SZ));
            if (t == S_SZ - 1) {
                float* tail = out + (size_t)B_SZ * S_SZ * H_SZ;
                *(f32x4*)(tail + hoff + jbase) = hv4;
                *(f32x4*)(tail + (size_t)B_SZ * H_SZ + hoff + jbase) = cv4;
            }
            if (l2ok) {
                *(u64*)(hnx + hoff + jbase) = ph8.u;
                *(u64*)(cnx + hoff + jbase) = pc8.u;
            } else {
                coh_store((u64*)(hnx + hoff + jbase), ph8.u);
                coh_store((u64*)(cnx + hoff + jbase), pc8.u);
            }
        } else {
            // ---- X side: prefetch x[t+1] (hides under H's epilogue) ----
            const int tp = (t + 1 < S_SZ) ? t + 1 : t;
            if constexpr (XB) {
                const __bf16* xpn = xrowb + (size_t)tp * D_SZ;
                #pragma unroll
                for (int kk = 0; kk < 16; ++kk)
                    xbf[kk] = *(const bf16x8*)(xpn + kk * 32 + kbase);
            } else {
                const float* xpn = xrow + (size_t)tp * D_SZ;
                #pragma unroll
                for (int kk = 0; kk < 16; ++kk) {
                    f32x4 u = *(const f32x4*)(xpn + kk * 32 + kbase);
                    f32x4 v = *(const f32x4*)(xpn + kk * 32 + kbase + 4);
                    bf16x8 a;
                    a[0] = (__bf16)u[0]; a[1] = (__bf16)u[1]; a[2] = (__bf16)u[2]; a[3] = (__bf16)u[3];
                    a[4] = (__bf16)v[0]; a[5] = (__bf16)v[1]; a[6] = (__bf16)v[2]; a[7] = (__bf16)v[3];
                    xbf[kk] = a;
                }
            }
        }

        // ---- group flag barrier (round-11/13 protocol verbatim) ----
        if (t < S_SZ - 1) {
            __syncthreads();   // per-wave vmcnt(0) drain before s_barrier:
                               // H-side state stores are in L2/LLC
            if (tid == 0)
                __hip_atomic_store(myflag, t + 1, __ATOMIC_RELAXED,
                                   __HIP_MEMORY_SCOPE_AGENT);
            const int target = t + 1;
            for (;;) {
                int v = __hip_atomic_load(pollp, __ATOMIC_RELAXED,
                                          __HIP_MEMORY_SCOPE_AGENT);
                if (__all(v >= target)) break;
                __builtin_amdgcn_s_sleep(1);
            }
            if (l2ok)
                asm volatile("buffer_inv sc0" ::: "memory");  // vL1 only
            __builtin_amdgcn_sched_barrier(0);
        }
    }
}

extern "C" void kernel_launch(void* const* d_in, const int* in_sizes, int n_in,
                              void* d_out, int out_size, void* d_ws, size_t ws_size,
                              hipStream_t stream) {
    const float* x  = (const float*)d_in[0];
    const float* ts = (const float*)d_in[1];
    const float* We = (const float*)d_in[2];
    const float* be = (const float*)d_in[3];
    const float* Ui = (const float*)d_in[4];
    const float* Vi = (const float*)d_in[5];
    const float* bi = (const float*)d_in[6];
    const float* Uf = (const float*)d_in[7];
    const float* Vf = (const float*)d_in[8];
    const float* bf = (const float*)d_in[9];
    const float* Uc = (const float*)d_in[10];
    const float* Vc = (const float*)d_in[11];
    const float* bc = (const float*)d_in[12];
    const float* Uo = (const float*)d_in[13];
    const float* Vo = (const float*)d_in[14];
    const float* bo = (const float*)d_in[15];

    char* ws = (char*)d_ws;
    int* flags = (int*)ws;
    __bf16* state = (__bf16*)(ws + STATE_OFF);
    __bf16* GwT = (__bf16*)(ws + GWT_OFF_BYTES);
    __bf16* WeT = (__bf16*)(ws + WET_OFF_BYTES);

    // zero flags (step + xcc) + parity-0 state (h0 = c0 = 0)
    hipMemsetAsync(ws, 0, FLAGS_BYTES + 1048576, stream);
    prep_weights<<<2560, 256, 0, stream>>>(We, Ui, Vi, Uf, Vf, Uc, Vc, Uo, Vo, GwT, WeT);

    if (ws_size >= (size_t)XB_OFF_BYTES + XB_BYTES) {
        __bf16* xb = (__bf16*)(ws + XB_OFF_BYTES);
        xcvt<<<(int)(B_SZ * S_SZ * D_SZ / 8 / 256), 256, 0, stream>>>(x, xb);
        lstm_persist<true><<<256, 512, 0, stream>>>(x, xb, ts, bi, bf, bc, bo, be,
                                                    GwT, WeT, state, flags,
                                                    (float*)d_out);
    } else {
        lstm_persist<false><<<256, 512, 0, stream>>>(x, nullptr, ts, bi, bf, bc, bo,
                                                     be, GwT, WeT, state, flags,
                                                     (float*)d_out);
    }
}

// Round 15
// 5076.339 us; speedup vs baseline: 1.0061x; 1.0061x over previous
//
#include <hip/hip_runtime.h>

#define B_SZ 512
#define S_SZ 256
#define D_SZ 512
#define H_SZ 512

typedef __bf16 bf16x8 __attribute__((ext_vector_type(8)));
typedef __bf16 bf16x4 __attribute__((ext_vector_type(4)));
typedef float f32x4 __attribute__((ext_vector_type(4)));
typedef int i32x4 __attribute__((ext_vector_type(4)));
typedef unsigned long long u64;

// ---------------- ws layout (bytes) ----------------
// [0, 32KB)       : step flags: 8 groups x 32 WG-slots x 128B
// [32KB, 64KB)    : xcc flags:  8 groups x 32 WG-slots x 128B
// [64KB, +1MB)    : state parity 0: h0 (512x512 bf16) then cf0 (c*f_att)
// [+1MB, +2MB)    : state parity 1
// [2162688, +4MB) : GwT 4*512*1024 bf16 (g, j, k)
// [6356992, +.5MB): WeT 512*512 bf16 (j, k)
// [6881280, +128MB): x_bf16 (optional, if ws_size permits)
#define FLAGS_BYTES 65536
#define STATE_OFF FLAGS_BYTES
#define STATE_PAR_ELEMS (2 * H_SZ * B_SZ)
#define GWT_OFF_BYTES (STATE_OFF + 2097152)
#define WET_OFF_BYTES (GWT_OFF_BYTES + 4194304)
#define XB_OFF_BYTES (WET_OFF_BYTES + 524288)
#define XB_BYTES ((size_t)B_SZ * S_SZ * D_SZ * 2)

// XOR swizzle: 2-way max bank aliasing on ds_read_b128 (free per m136)
#define SWZ(j, k) ((k) ^ (((j) & 7) << 3) ^ ((((j) >> 3) & 1) << 6))

__device__ __forceinline__ float sigmoidf_(float v) {
    return 1.f / (1.f + __expf(-v));
}
__device__ __forceinline__ float tanhf_(float v) {
    return 1.f - 2.f / (1.f + __expf(2.f * v));
}

// LLC-coherent accesses (fallback + flag protocol): relaxed agent atomics ->
// sc0 sc1 on BOTH store and load sides (same coherence point => live).
// [R12 lesson: never mix sc-scopes across a signal/poll pair.]
__device__ __forceinline__ u64 coh_load(const u64* p) {
    return __hip_atomic_load(p, __ATOMIC_RELAXED, __HIP_MEMORY_SCOPE_AGENT);
}
__device__ __forceinline__ void coh_store(u64* p, u64 v) {
    __hip_atomic_store(p, v, __ATOMIC_RELAXED, __HIP_MEMORY_SCOPE_AGENT);
}

__global__ __launch_bounds__(256) void prep_weights(
    const float* __restrict__ We,
    const float* __restrict__ Ui, const float* __restrict__ Vi,
    const float* __restrict__ Uf, const float* __restrict__ Vf,
    const float* __restrict__ Uc, const float* __restrict__ Vc,
    const float* __restrict__ Uo, const float* __restrict__ Vo,
    __bf16* __restrict__ GwT, __bf16* __restrict__ WeT)
{
    const int bid = blockIdx.x;
    const int tid = threadIdx.x;
    if (bid < 2048) {
        const int g = bid >> 9;
        const int j = bid & 511;
        const float* U = (g == 0) ? Ui : (g == 1) ? Uf : (g == 2) ? Uc : Uo;
        const float* V = (g == 0) ? Vi : (g == 1) ? Vf : (g == 2) ? Vc : Vo;
        __bf16* dst = GwT + ((size_t)(g * 512 + j) << 10);
        for (int k = tid; k < 1024; k += 256) {
            float v = (k < 512) ? U[k * 512 + j] : V[(k - 512) * 512 + j];
            dst[k] = (__bf16)v;
        }
    } else {
        const int j = bid - 2048;
        __bf16* dst = WeT + ((size_t)j << 9);
        for (int k = tid; k < 512; k += 256) {
            dst[k] = (__bf16)We[k * 512 + j];
        }
    }
}

// One-time x f32 -> bf16 (numerics identical to per-step conversion).
__global__ __launch_bounds__(256) void xcvt(const float* __restrict__ x,
                                            __bf16* __restrict__ xb)
{
    const size_t i = ((size_t)blockIdx.x * 256 + threadIdx.x) * 8;
    f32x4 a = *(const f32x4*)(x + i);
    f32x4 b = *(const f32x4*)(x + i + 4);
    bf16x8 o;
    o[0] = (__bf16)a[0]; o[1] = (__bf16)a[1]; o[2] = (__bf16)a[2]; o[3] = (__bf16)a[3];
    o[4] = (__bf16)b[0]; o[5] = (__bf16)b[1]; o[6] = (__bf16)b[2]; o[7] = (__bf16)b[3];
    *(bf16x8*)(xb + i) = o;
}

union HU { i32x4 q; u64 u[2]; bf16x8 v; };

// 16B state load: l2ok -> plain cached load (vL1 invalidated at acquire);
// else LLC agent-atomic pair.
#define LD16(dst, basep, kkidx) do {                                          \
    if (l2ok) { (dst).q = *(const i32x4*)((basep) + (kkidx) * 32); }          \
    else { const u64* _p = (const u64*)((basep) + (kkidx) * 32);              \
           (dst).u[0] = coh_load(_p); (dst).u[1] = coh_load(_p + 1); }        \
} while (0)

// consume 4 kk-slices of h/c from a chunk buffer (static indices)
#define CONSUME(hbuf, cbuf, kk0) do {                                         \
    _Pragma("unroll")                                                         \
    for (int i_ = 0; i_ < 4; ++i_) {                                          \
        const int kk_ = (kk0) + i_;                                           \
        const int k_ = SWZ(alr, 512 + kk_ * 32 + kbase);                      \
        bf16x8 w0 = *(const bf16x8*)&wlds[0][alr][k_];                        \
        bf16x8 w1 = *(const bf16x8*)&wlds[1][alr][k_];                        \
        bf16x8 w2 = *(const bf16x8*)&wlds[2][alr][k_];                        \
        bf16x8 w3 = *(const bf16x8*)&wlds[3][alr][k_];                        \
        bf16x8 we = *(const bf16x8*)&welds[alr][SWZ(alr, kk_ * 32 + kbase)];  \
        a0 = __builtin_amdgcn_mfma_f32_16x16x32_bf16(w0, (hbuf)[i_].v, a0, 0, 0, 0); \
        a1 = __builtin_amdgcn_mfma_f32_16x16x32_bf16(w1, (hbuf)[i_].v, a1, 0, 0, 0); \
        a2 = __builtin_amdgcn_mfma_f32_16x16x32_bf16(w2, (hbuf)[i_].v, a2, 0, 0, 0); \
        a3 = __builtin_amdgcn_mfma_f32_16x16x32_bf16(w3, (hbuf)[i_].v, a3, 0, 0, 0); \
        a4 = __builtin_amdgcn_mfma_f32_16x16x32_bf16(we, (cbuf)[i_].v, a4, 0, 0, 0); \
    }                                                                         \
} while (0)

#define LOADCH(hbuf, cbuf, kk0) do {                                          \
    _Pragma("unroll")                                                         \
    for (int i_ = 0; i_ < 4; ++i_) {                                          \
        LD16((hbuf)[i_], hb, (kk0) + i_);                                     \
        LD16((cbuf)[i_], cb, (kk0) + i_);                                     \
    }                                                                         \
} while (0)

// Persistent recurrent kernel, K-SPLIT 8-wave v2.
// 256 WGs x 512 thr, 1 WG/CU (160KB LDS) -> 2 waves/SIMD.
// Waves 0-3 (X): x@U partials -> red (conflict-free [4][16][64] layout).
// Waves 4-7 (H): chunked state loads (2-deep pipeline, 64 VGPR peak) +
// h@V + cf@We, merge red, elementwise, publish.
// __launch_bounds__(512,2): truthful occupancy -> 256-VGPR cap (R14 spilled
// at the heuristic 128-cap). Sync/coherence = R11/R13 proven recipe.
template <bool XB>
__global__ __launch_bounds__(512, 2) void lstm_persist(
    const float* __restrict__ x, const __bf16* __restrict__ xb,
    const float* __restrict__ tseq,
    const float* __restrict__ b_i, const float* __restrict__ b_f,
    const float* __restrict__ b_c, const float* __restrict__ b_o,
    const float* __restrict__ b_e,
    const __bf16* __restrict__ GwT, const __bf16* __restrict__ WeT,
    __bf16* __restrict__ state, int* __restrict__ flags,
    float* __restrict__ out)
{
    __shared__ __align__(16) __bf16 wlds[4][16][1024];   // 128 KB
    __shared__ __align__(16) __bf16 welds[16][512];      // 16 KB
    __shared__ __align__(16) float red[4][16][64];       // 16 KB -> 160 KiB

    const int tid = threadIdx.x;
    const int bid = blockIdx.x;
    const int rblk = bid & 7;
    const int cblk = bid >> 3;
    const int j0 = cblk << 4;
    const int wave = tid >> 6;       // 0..7
    const int side = wave >> 2;      // 0 = X (x@U), 1 = H (h@V + We + epilogue)
    const int wrow = wave & 3;       // row sub-block
    const int lane = tid & 63;
    const int alr = lane & 15;       // weight row j (A-frag row)
    const int hq = lane >> 4;        // k-subgroup / C j-quad
    const int kbase = hq * 8;

    // ---- stage weights into LDS, swizzled (once; 512 threads) ----
    for (int e = tid * 8; e < 4 * 16 * 1024; e += 512 * 8) {
        const int g = e >> 14;
        const int j = (e >> 10) & 15;
        const int k = e & 1023;
        *(uint4*)&wlds[g][j][SWZ(j, k)] =
            *(const uint4*)&GwT[((size_t)(g * 512 + j0 + j) << 10) + k];
    }
    for (int e = tid * 8; e < 16 * 512; e += 512 * 8) {
        const int j = e >> 9;
        const int k = e & 511;
        *(uint4*)&welds[j][SWZ(j, k)] =
            *(const uint4*)&WeT[((size_t)(j0 + j) << 9) + k];
    }
    __syncthreads();

    const int brow = rblk * 64 + wrow * 16 + alr;   // batch row (wave-pair)
    const int jbase = j0 + hq * 4;                   // 4 consecutive j (C rows)
    const f32x4 Bi4 = *(const f32x4*)(b_i + jbase);
    const f32x4 Bf4 = *(const f32x4*)(b_f + jbase);
    const f32x4 Bc4 = *(const f32x4*)(b_c + jbase);
    const f32x4 Bo4 = *(const f32x4*)(b_o + jbase);
    const f32x4 Be4 = *(const f32x4*)(b_e + jbase);

    const float* xrow = x + (size_t)brow * S_SZ * D_SZ;
    const __bf16* xrowb = XB ? xb + (size_t)brow * S_SZ * D_SZ : nullptr;
    const float* tsrow = tseq + (size_t)brow * S_SZ;
    const size_t hoff = (size_t)brow * H_SZ;
    float* outrow = out + (size_t)brow * S_SZ * H_SZ + jbase;

    // step-flag slots (128B stride) + per-lane poll pointer
    int* gflags = flags + rblk * 32 * 32;
    int* myflag = gflags + cblk * 32;
    const int* pollp = gflags + (lane & 31) * 32;

    // ---- XCD-locality check (one-time, proven rounds 6/9/10/11/13) ----
    int* xgrp = flags + 8192 + rblk * 32 * 32;
    unsigned xcc;
    asm volatile("s_getreg_b32 %0, hwreg(HW_REG_XCC_ID)" : "=s"(xcc));
    if (tid == 0)
        __hip_atomic_store(xgrp + cblk * 32, (int)xcc + 1,
                           __ATOMIC_RELAXED, __HIP_MEMORY_SCOPE_AGENT);
    int vx;
    const int* xpoll = xgrp + (lane & 31) * 32;
    for (;;) {
        vx = __hip_atomic_load(xpoll, __ATOMIC_RELAXED, __HIP_MEMORY_SCOPE_AGENT);
        if (__all(vx != 0)) break;
        __builtin_amdgcn_s_sleep(1);
    }
    const bool l2ok = __all(vx == __shfl(vx, 0, 64));

    // X-side prologue: x[0] fragments
    bf16x8 xbf[16];
    if (side == 0) {
        if constexpr (XB) {
            #pragma unroll
            for (int kk = 0; kk < 16; ++kk)
                xbf[kk] = *(const bf16x8*)(xrowb + kk * 32 + kbase);
        } else {
            #pragma unroll
            for (int kk = 0; kk < 16; ++kk) {
                f32x4 u = *(const f32x4*)(xrow + kk * 32 + kbase);
                f32x4 v = *(const f32x4*)(xrow + kk * 32 + kbase + 4);
                bf16x8 a;
                a[0] = (__bf16)u[0]; a[1] = (__bf16)u[1]; a[2] = (__bf16)u[2]; a[3] = (__bf16)u[3];
                a[4] = (__bf16)v[0]; a[5] = (__bf16)v[1]; a[6] = (__bf16)v[2]; a[7] = (__bf16)v[3];
                xbf[kk] = a;
            }
        }
    }

    for (int t = 0; t < S_SZ; ++t) {
        const __bf16* hp = state + (size_t)(t & 1) * STATE_PAR_ELEMS;
        const __bf16* cp = hp + (size_t)H_SZ * B_SZ;
        __bf16* hnx = state + (size_t)((t + 1) & 1) * STATE_PAR_ELEMS;
        __bf16* cnx = hnx + (size_t)H_SZ * B_SZ;

        f32x4 a0, a1, a2, a3, a4;

        if (side == 0) {
            // ---- X side: x@U partials (no bias) ----
            f32x4 p0 = {0,0,0,0}, p1 = {0,0,0,0}, p2 = {0,0,0,0}, p3 = {0,0,0,0};
            #pragma unroll
            for (int kk = 0; kk < 16; ++kk) {
                const int k = SWZ(alr, kk * 32 + kbase);
                bf16x8 w0 = *(const bf16x8*)&wlds[0][alr][k];
                bf16x8 w1 = *(const bf16x8*)&wlds[1][alr][k];
                bf16x8 w2 = *(const bf16x8*)&wlds[2][alr][k];
                bf16x8 w3 = *(const bf16x8*)&wlds[3][alr][k];
                p0 = __builtin_amdgcn_mfma_f32_16x16x32_bf16(w0, xbf[kk], p0, 0, 0, 0);
                p1 = __builtin_amdgcn_mfma_f32_16x16x32_bf16(w1, xbf[kk], p1, 0, 0, 0);
                p2 = __builtin_amdgcn_mfma_f32_16x16x32_bf16(w2, xbf[kk], p2, 0, 0, 0);
                p3 = __builtin_amdgcn_mfma_f32_16x16x32_bf16(w3, xbf[kk], p3, 0, 0, 0);
            }
            // conflict-free scalar stores: bank = lane%32 -> 2 lanes/bank
            #pragma unroll
            for (int e = 0; e < 4; ++e) {
                red[wrow][e][lane]      = p0[e];
                red[wrow][4 + e][lane]  = p1[e];
                red[wrow][8 + e][lane]  = p2[e];
                red[wrow][12 + e][lane] = p3[e];
            }
        } else {
            // ---- H side: chunked state loads (2-deep) + h@V + cf@We ----
            const __bf16* hb = hp + hoff + kbase;
            const __bf16* cb = cp + hoff + kbase;
            HU hA[4], cA[4], hB[4], cB[4];
            a0 = Bi4; a1 = Bf4; a2 = Bc4; a3 = Bo4; a4 = Be4;
            LOADCH(hA, cA, 0);
            LOADCH(hB, cB, 4);
            CONSUME(hA, cA, 0);
            LOADCH(hA, cA, 8);
            CONSUME(hB, cB, 4);
            LOADCH(hB, cB, 12);
            CONSUME(hA, cA, 8);
            CONSUME(hB, cB, 12);
        }

        __syncthreads();   // red visible to H side

        if (side == 1) {
            // ---- H side: merge partials, elementwise, publish ----
            #pragma unroll
            for (int e = 0; e < 4; ++e) {
                a0[e] += red[wrow][e][lane];
                a1[e] += red[wrow][4 + e][lane];
                a2[e] += red[wrow][8 + e][lane];
                a3[e] += red[wrow][12 + e][lane];
            }

            const float fa = (t + 1 < S_SZ) ? tsrow[t + 1] : 0.f;
            f32x4 hv4, cv4;
            union { bf16x4 v; u64 u; } ph8, pc8;
            #pragma unroll
            for (int e = 0; e < 4; ++e) {
                float it = sigmoidf_(a0[e]);
                float ft = sigmoidf_(a1[e]);
                float gt = tanhf_(a2[e]);
                float ot = sigmoidf_(a3[e]);
                float ctl = tanhf_(a4[e]);
                float cv = ft * ctl + it * gt;
                float hv = ot * tanhf_(cv);
                hv4[e] = hv; cv4[e] = cv;
                ph8.v[e] = (__bf16)hv;
                pc8.v[e] = (__bf16)(cv * fa);
            }
            __builtin_nontemporal_store(hv4, (f32x4*)(outrow + (size_t)t * H_SZ));
            if (t == S_SZ - 1) {
                float* tail = out + (size_t)B_SZ * S_SZ * H_SZ;
                *(f32x4*)(tail + hoff + jbase) = hv4;
                *(f32x4*)(tail + (size_t)B_SZ * H_SZ + hoff + jbase) = cv4;
            }
            if (l2ok) {
                *(u64*)(hnx + hoff + jbase) = ph8.u;
                *(u64*)(cnx + hoff + jbase) = pc8.u;
            } else {
                coh_store((u64*)(hnx + hoff + jbase), ph8.u);
                coh_store((u64*)(cnx + hoff + jbase), pc8.u);
            }
        } else {
            // ---- X side: prefetch x[t+1] (hides under H's epilogue) ----
            const int tp = (t + 1 < S_SZ) ? t + 1 : t;
            if constexpr (XB) {
                const __bf16* xpn = xrowb + (size_t)tp * D_SZ;
                #pragma unroll
                for (int kk = 0; kk < 16; ++kk)
                    xbf[kk] = *(const bf16x8*)(xpn + kk * 32 + kbase);
            } else {
                const float* xpn = xrow + (size_t)tp * D_SZ;
                #pragma unroll
                for (int kk = 0; kk < 16; ++kk) {
                    f32x4 u = *(const f32x4*)(xpn + kk * 32 + kbase);
                    f32x4 v = *(const f32x4*)(xpn + kk * 32 + kbase + 4);
                    bf16x8 a;
                    a[0] = (__bf16)u[0]; a[1] = (__bf16)u[1]; a[2] = (__bf16)u[2]; a[3] = (__bf16)u[3];
                    a[4] = (__bf16)v[0]; a[5] = (__bf16)v[1]; a[6] = (__bf16)v[2]; a[7] = (__bf16)v[3];
                    xbf[kk] = a;
                }
            }
        }

        // ---- group flag barrier (round-11/13 protocol verbatim) ----
        if (t < S_SZ - 1) {
            __syncthreads();   // per-wave vmcnt(0) drain: state stores visible
            if (tid == 0)
                __hip_atomic_store(myflag, t + 1, __ATOMIC_RELAXED,
                                   __HIP_MEMORY_SCOPE_AGENT);
            const int target = t + 1;
            for (;;) {
                int v = __hip_atomic_load(pollp, __ATOMIC_RELAXED,
                                          __HIP_MEMORY_SCOPE_AGENT);
                if (__all(v >= target)) break;
                __builtin_amdgcn_s_sleep(1);
            }
            if (l2ok)
                asm volatile("buffer_inv sc0" ::: "memory");  // vL1 only
            __builtin_amdgcn_sched_barrier(0);
        }
    }
}

extern "C" void kernel_launch(void* const* d_in, const int* in_sizes, int n_in,
                              void* d_out, int out_size, void* d_ws, size_t ws_size,
                              hipStream_t stream) {
    const float* x  = (const float*)d_in[0];
    const float* ts = (const float*)d_in[1];
    const float* We = (const float*)d_in[2];
    const float* be = (const float*)d_in[3];
    const float* Ui = (const float*)d_in[4];
    const float* Vi = (const float*)d_in[5];
    const float* bi = (const float*)d_in[6];
    const float* Uf = (const float*)d_in[7];
    const float* Vf = (const float*)d_in[8];
    const float* bf = (const float*)d_in[9];
    const float* Uc = (const float*)d_in[10];
    const float* Vc = (const float*)d_in[11];
    const float* bc = (const float*)d_in[12];
    const float* Uo = (const float*)d_in[13];
    const float* Vo = (const float*)d_in[14];
    const float* bo = (const float*)d_in[15];

    char* ws = (char*)d_ws;
    int* flags = (int*)ws;
    __bf16* state = (__bf16*)(ws + STATE_OFF);
    __bf16* GwT = (__bf16*)(ws + GWT_OFF_BYTES);
    __bf16* WeT = (__bf16*)(ws + WET_OFF_BYTES);

    // zero flags (step + xcc) + parity-0 state (h0 = c0 = 0)
    hipMemsetAsync(ws, 0, FLAGS_BYTES + 1048576, stream);
    prep_weights<<<2560, 256, 0, stream>>>(We, Ui, Vi, Uf, Vf, Uc, Vc, Uo, Vo, GwT, WeT);

    if (ws_size >= (size_t)XB_OFF_BYTES + XB_BYTES) {
        __bf16* xb = (__bf16*)(ws + XB_OFF_BYTES);
        xcvt<<<(int)(B_SZ * S_SZ * D_SZ / 8 / 256), 256, 0, stream>>>(x, xb);
        lstm_persist<true><<<256, 512, 0, stream>>>(x, xb, ts, bi, bf, bc, bo, be,
                                                    GwT, WeT, state, flags,
                                                    (float*)d_out);
    } else {
        lstm_persist<false><<<256, 512, 0, stream>>>(x, nullptr, ts, bi, bf, bc, bo,
                                                     be, GwT, WeT, state, flags,
                                                     (float*)d_out);
    }
}

// Round 16
// 1860.662 us; speedup vs baseline: 2.7450x; 2.7282x over previous
//
#include <hip/hip_runtime.h>

#define B_SZ 512
#define S_SZ 256
#define D_SZ 512
#define H_SZ 512

typedef __bf16 bf16x8 __attribute__((ext_vector_type(8)));
typedef __bf16 bf16x4 __attribute__((ext_vector_type(4)));
typedef float f32x4 __attribute__((ext_vector_type(4)));
typedef int i32x4 __attribute__((ext_vector_type(4)));
typedef unsigned long long u64;

// ---------------- ws layout (bytes) ----------------
// [0, 64KB)       : step flags: 8 groups x 64 WG-slots x 128B
// [64KB, 128KB)   : xcc flags:  8 groups x 64 WG-slots x 128B
// [128KB, +1MB)   : state parity 0: h0 (512x512 bf16) then cf0 (c*f_att)
// [+1MB, +2MB)    : state parity 1
// then GwT (4MB), WeT (.5MB), x_bf16 (128MB, optional)
#define FLAGS_BYTES 131072
#define GRPI 2048                 // ints per flag group (64 slots x 32)
#define XCCI 16384                // int offset of xcc flag region
#define STATE_OFF FLAGS_BYTES
#define STATE_PAR_ELEMS (2 * H_SZ * B_SZ)
#define GWT_OFF_BYTES (STATE_OFF + 2097152)
#define WET_OFF_BYTES (GWT_OFF_BYTES + 4194304)
#define XB_OFF_BYTES (WET_OFF_BYTES + 524288)
#define XB_BYTES ((size_t)B_SZ * S_SZ * D_SZ * 2)

// XOR swizzle: 2-way max bank aliasing on ds_read_b128 (free per m136)
#define SWZ(j, k) ((k) ^ (((j) & 7) << 3) ^ ((((j) >> 3) & 1) << 6))

__device__ __forceinline__ float sigmoidf_(float v) {
    return 1.f / (1.f + __expf(-v));
}
__device__ __forceinline__ float tanhf_(float v) {
    return 1.f - 2.f / (1.f + __expf(2.f * v));
}

// LLC-coherent accesses (fallback + flag protocol): relaxed agent atomics ->
// sc0 sc1 on BOTH sides (same coherence point => live). [R12 lesson: never
// mix sc-scopes across a signal/poll pair.]
__device__ __forceinline__ u64 coh_load(const u64* p) {
    return __hip_atomic_load(p, __ATOMIC_RELAXED, __HIP_MEMORY_SCOPE_AGENT);
}
__device__ __forceinline__ void coh_store(u64* p, u64 v) {
    __hip_atomic_store(p, v, __ATOMIC_RELAXED, __HIP_MEMORY_SCOPE_AGENT);
}

__global__ __launch_bounds__(256) void prep_weights(
    const float* __restrict__ We,
    const float* __restrict__ Ui, const float* __restrict__ Vi,
    const float* __restrict__ Uf, const float* __restrict__ Vf,
    const float* __restrict__ Uc, const float* __restrict__ Vc,
    const float* __restrict__ Uo, const float* __restrict__ Vo,
    __bf16* __restrict__ GwT, __bf16* __restrict__ WeT)
{
    const int bid = blockIdx.x;
    const int tid = threadIdx.x;
    if (bid < 2048) {
        const int g = bid >> 9;
        const int j = bid & 511;
        const float* U = (g == 0) ? Ui : (g == 1) ? Uf : (g == 2) ? Uc : Uo;
        const float* V = (g == 0) ? Vi : (g == 1) ? Vf : (g == 2) ? Vc : Vo;
        __bf16* dst = GwT + ((size_t)(g * 512 + j) << 10);
        for (int k = tid; k < 1024; k += 256) {
            float v = (k < 512) ? U[k * 512 + j] : V[(k - 512) * 512 + j];
            dst[k] = (__bf16)v;
        }
    } else {
        const int j = bid - 2048;
        __bf16* dst = WeT + ((size_t)j << 9);
        for (int k = tid; k < 512; k += 256) {
            dst[k] = (__bf16)We[k * 512 + j];
        }
    }
}

// One-time x f32 -> bf16 (numerics identical to per-step conversion).
__global__ __launch_bounds__(256) void xcvt(const float* __restrict__ x,
                                            __bf16* __restrict__ xb)
{
    const size_t i = ((size_t)blockIdx.x * 256 + threadIdx.x) * 8;
    f32x4 a = *(const f32x4*)(x + i);
    f32x4 b = *(const f32x4*)(x + i + 4);
    bf16x8 o;
    o[0] = (__bf16)a[0]; o[1] = (__bf16)a[1]; o[2] = (__bf16)a[2]; o[3] = (__bf16)a[3];
    o[4] = (__bf16)b[0]; o[5] = (__bf16)b[1]; o[6] = (__bf16)b[2]; o[7] = (__bf16)b[3];
    *(bf16x8*)(xb + i) = o;
}

union HU { i32x4 q; u64 u[2]; bf16x8 v; };

#define LD16(dst, basep, kkidx) do {                                          \
    if (l2ok) { (dst).q = *(const i32x4*)((basep) + (kkidx) * 32); }          \
    else { const u64* _p = (const u64*)((basep) + (kkidx) * 32);              \
           (dst).u[0] = coh_load(_p); (dst).u[1] = coh_load(_p + 1); }        \
} while (0)

#define LOADCH(hbuf, cbuf, kk0) do {                                          \
    _Pragma("unroll")                                                         \
    for (int i_ = 0; i_ < 4; ++i_) {                                          \
        LD16((hbuf)[i_], hb, (kk0) + i_);                                     \
        LD16((cbuf)[i_], cb, (kk0) + i_);                                     \
    }                                                                         \
} while (0)

// ============================================================================
// V1: proven round-13 kernel (256 WGs x 256 thr, 1 WG/CU, 16 cols).
// Only flag offsets updated to the enlarged layout.
// ============================================================================
template <bool XB>
__global__ __launch_bounds__(256, 1) void lstm_v1(
    const float* __restrict__ x, const __bf16* __restrict__ xb,
    const float* __restrict__ tseq,
    const float* __restrict__ b_i, const float* __restrict__ b_f,
    const float* __restrict__ b_c, const float* __restrict__ b_o,
    const float* __restrict__ b_e,
    const __bf16* __restrict__ GwT, const __bf16* __restrict__ WeT,
    __bf16* __restrict__ state, int* __restrict__ flags,
    float* __restrict__ out)
{
    __shared__ __align__(16) __bf16 wlds[4][16][1024];
    __shared__ __align__(16) __bf16 welds[16][512];

    const int tid = threadIdx.x;
    const int bid = blockIdx.x;
    const int rblk = bid & 7;
    const int cblk = bid >> 3;
    const int j0 = cblk << 4;
    const int wave = tid >> 6;
    const int lane = tid & 63;
    const int alr = lane & 15;
    const int hq = lane >> 4;
    const int kbase = hq * 8;

    for (int e = tid * 8; e < 4 * 16 * 1024; e += 256 * 8) {
        const int g = e >> 14;
        const int j = (e >> 10) & 15;
        const int k = e & 1023;
        *(uint4*)&wlds[g][j][SWZ(j, k)] =
            *(const uint4*)&GwT[((size_t)(g * 512 + j0 + j) << 10) + k];
    }
    for (int e = tid * 8; e < 16 * 512; e += 256 * 8) {
        const int j = e >> 9;
        const int k = e & 511;
        *(uint4*)&welds[j][SWZ(j, k)] =
            *(const uint4*)&WeT[((size_t)(j0 + j) << 9) + k];
    }
    __syncthreads();

    bf16x8 wxr[8][4];
    #pragma unroll
    for (int kk = 0; kk < 8; ++kk)
        #pragma unroll
        for (int g = 0; g < 4; ++g)
            wxr[kk][g] = *(const bf16x8*)&wlds[g][alr][SWZ(alr, kk * 32 + kbase)];

    const int brow = rblk * 64 + wave * 16 + alr;
    const int jbase = j0 + hq * 4;
    const f32x4 Bi4 = *(const f32x4*)(b_i + jbase);
    const f32x4 Bf4 = *(const f32x4*)(b_f + jbase);
    const f32x4 Bc4 = *(const f32x4*)(b_c + jbase);
    const f32x4 Bo4 = *(const f32x4*)(b_o + jbase);
    const f32x4 Be4 = *(const f32x4*)(b_e + jbase);

    const float* xrow = x + (size_t)brow * S_SZ * D_SZ;
    const __bf16* xrowb = XB ? xb + (size_t)brow * S_SZ * D_SZ : nullptr;
    const float* tsrow = tseq + (size_t)brow * S_SZ;
    const size_t hoff = (size_t)brow * H_SZ;
    float* outrow = out + (size_t)brow * S_SZ * H_SZ + jbase;

    int* gflags = flags + rblk * GRPI;
    int* myflag = gflags + cblk * 32;
    const int* pollp = gflags + (lane & 31) * 32;

    int* xgrp = flags + XCCI + rblk * GRPI;
    unsigned xcc;
    asm volatile("s_getreg_b32 %0, hwreg(HW_REG_XCC_ID)" : "=s"(xcc));
    if (tid == 0)
        __hip_atomic_store(xgrp + cblk * 32, (int)xcc + 1,
                           __ATOMIC_RELAXED, __HIP_MEMORY_SCOPE_AGENT);
    int vx;
    const int* xpoll = xgrp + (lane & 31) * 32;
    for (;;) {
        vx = __hip_atomic_load(xpoll, __ATOMIC_RELAXED, __HIP_MEMORY_SCOPE_AGENT);
        if (__all(vx != 0)) break;
        __builtin_amdgcn_s_sleep(1);
    }
    const bool l2ok = __all(vx == __shfl(vx, 0, 64));

    bf16x8 xbf[16];
    if constexpr (XB) {
        #pragma unroll
        for (int kk = 0; kk < 16; ++kk)
            xbf[kk] = *(const bf16x8*)(xrowb + kk * 32 + kbase);
    } else {
        #pragma unroll
        for (int kk = 0; kk < 16; ++kk) {
            f32x4 u = *(const f32x4*)(xrow + kk * 32 + kbase);
            f32x4 v = *(const f32x4*)(xrow + kk * 32 + kbase + 4);
            bf16x8 a;
            a[0] = (__bf16)u[0]; a[1] = (__bf16)u[1]; a[2] = (__bf16)u[2]; a[3] = (__bf16)u[3];
            a[4] = (__bf16)v[0]; a[5] = (__bf16)v[1]; a[6] = (__bf16)v[2]; a[7] = (__bf16)v[3];
            xbf[kk] = a;
        }
    }

    for (int t = 0; t < S_SZ; ++t) {
        const __bf16* hp = state + (size_t)(t & 1) * STATE_PAR_ELEMS;
        const __bf16* cp = hp + (size_t)H_SZ * B_SZ;
        __bf16* hnx = state + (size_t)((t + 1) & 1) * STATE_PAR_ELEMS;
        __bf16* cnx = hnx + (size_t)H_SZ * B_SZ;

        const float fa = (t + 1 < S_SZ) ? tsrow[t + 1] : 0.f;
        HU hs[16], cs[16];
        if (l2ok) {
            const __bf16* hb = hp + hoff + kbase;
            const __bf16* cb = cp + hoff + kbase;
            #pragma unroll
            for (int kk = 0; kk < 16; ++kk) {
                hs[kk].q = *(const i32x4*)(hb + kk * 32);
                cs[kk].q = *(const i32x4*)(cb + kk * 32);
            }
        } else {
            #pragma unroll
            for (int kk = 0; kk < 16; ++kk) {
                const u64* ph = (const u64*)(hp + hoff + kbase + kk * 32);
                const u64* pc = (const u64*)(cp + hoff + kbase + kk * 32);
                hs[kk].u[0] = coh_load(ph);
                hs[kk].u[1] = coh_load(ph + 1);
                cs[kk].u[0] = coh_load(pc);
                cs[kk].u[1] = coh_load(pc + 1);
            }
        }

        f32x4 a0 = Bi4, a1 = Bf4, a2 = Bc4, a3 = Bo4, a4 = Be4;

        #pragma unroll
        for (int kk = 0; kk < 16; ++kk) {
            bf16x8 w0, w1, w2, w3;
            if (kk < 8) {
                w0 = wxr[kk][0]; w1 = wxr[kk][1]; w2 = wxr[kk][2]; w3 = wxr[kk][3];
            } else {
                const int k = SWZ(alr, kk * 32 + kbase);
                w0 = *(const bf16x8*)&wlds[0][alr][k];
                w1 = *(const bf16x8*)&wlds[1][alr][k];
                w2 = *(const bf16x8*)&wlds[2][alr][k];
                w3 = *(const bf16x8*)&wlds[3][alr][k];
            }
            a0 = __builtin_amdgcn_mfma_f32_16x16x32_bf16(w0, xbf[kk], a0, 0, 0, 0);
            a1 = __builtin_amdgcn_mfma_f32_16x16x32_bf16(w1, xbf[kk], a1, 0, 0, 0);
            a2 = __builtin_amdgcn_mfma_f32_16x16x32_bf16(w2, xbf[kk], a2, 0, 0, 0);
            a3 = __builtin_amdgcn_mfma_f32_16x16x32_bf16(w3, xbf[kk], a3, 0, 0, 0);
        }

        #pragma unroll
        for (int kk = 0; kk < 16; ++kk) {
            const int k = SWZ(alr, 512 + kk * 32 + kbase);
            bf16x8 w0 = *(const bf16x8*)&wlds[0][alr][k];
            bf16x8 w1 = *(const bf16x8*)&wlds[1][alr][k];
            bf16x8 w2 = *(const bf16x8*)&wlds[2][alr][k];
            bf16x8 w3 = *(const bf16x8*)&wlds[3][alr][k];
            bf16x8 we = *(const bf16x8*)&welds[alr][SWZ(alr, kk * 32 + kbase)];
            a0 = __builtin_amdgcn_mfma_f32_16x16x32_bf16(w0, hs[kk].v, a0, 0, 0, 0);
            a1 = __builtin_amdgcn_mfma_f32_16x16x32_bf16(w1, hs[kk].v, a1, 0, 0, 0);
            a2 = __builtin_amdgcn_mfma_f32_16x16x32_bf16(w2, hs[kk].v, a2, 0, 0, 0);
            a3 = __builtin_amdgcn_mfma_f32_16x16x32_bf16(w3, hs[kk].v, a3, 0, 0, 0);
            a4 = __builtin_amdgcn_mfma_f32_16x16x32_bf16(we, cs[kk].v, a4, 0, 0, 0);
        }

        const int tp = (t + 1 < S_SZ) ? t + 1 : t;
        f32x4 xf[32];
        if constexpr (XB) {
            const __bf16* xpn = xrowb + (size_t)tp * D_SZ;
            #pragma unroll
            for (int kk = 0; kk < 16; ++kk)
                xbf[kk] = *(const bf16x8*)(xpn + kk * 32 + kbase);
        } else {
            const float* xpn = xrow + (size_t)tp * D_SZ;
            #pragma unroll
            for (int kk = 0; kk < 16; ++kk) {
                xf[2 * kk]     = *(const f32x4*)(xpn + kk * 32 + kbase);
                xf[2 * kk + 1] = *(const f32x4*)(xpn + kk * 32 + kbase + 4);
            }
        }

        f32x4 hv4, cv4;
        union { bf16x4 v; u64 u; } ph8, pc8;
        #pragma unroll
        for (int e = 0; e < 4; ++e) {
            float it = sigmoidf_(a0[e]);
            float ft = sigmoidf_(a1[e]);
            float gt = tanhf_(a2[e]);
            float ot = sigmoidf_(a3[e]);
            float ctl = tanhf_(a4[e]);
            float cv = ft * ctl + it * gt;
            float hv = ot * tanhf_(cv);
            hv4[e] = hv; cv4[e] = cv;
            ph8.v[e] = (__bf16)hv;
            pc8.v[e] = (__bf16)(cv * fa);
        }
        __builtin_nontemporal_store(hv4, (f32x4*)(outrow + (size_t)t * H_SZ));
        if (t == S_SZ - 1) {
            float* tail = out + (size_t)B_SZ * S_SZ * H_SZ;
            *(f32x4*)(tail + hoff + jbase) = hv4;
            *(f32x4*)(tail + (size_t)B_SZ * H_SZ + hoff + jbase) = cv4;
        }

        if constexpr (!XB) {
            #pragma unroll
            for (int kk = 0; kk < 16; ++kk) {
                f32x4 u = xf[2 * kk], v = xf[2 * kk + 1];
                bf16x8 a;
                a[0] = (__bf16)u[0]; a[1] = (__bf16)u[1]; a[2] = (__bf16)u[2]; a[3] = (__bf16)u[3];
                a[4] = (__bf16)v[0]; a[5] = (__bf16)v[1]; a[6] = (__bf16)v[2]; a[7] = (__bf16)v[3];
                xbf[kk] = a;
            }
        }

        if (l2ok) {
            *(u64*)(hnx + hoff + jbase) = ph8.u;
            *(u64*)(cnx + hoff + jbase) = pc8.u;
        } else {
            coh_store((u64*)(hnx + hoff + jbase), ph8.u);
            coh_store((u64*)(cnx + hoff + jbase), pc8.u);
        }

        if (t < S_SZ - 1) {
            __syncthreads();
            if (tid == 0)
                __hip_atomic_store(myflag, t + 1, __ATOMIC_RELAXED,
                                   __HIP_MEMORY_SCOPE_AGENT);
            const int target = t + 1;
            for (;;) {
                int v = __hip_atomic_load(pollp, __ATOMIC_RELAXED,
                                          __HIP_MEMORY_SCOPE_AGENT);
                if (__all(v >= target)) break;
                __builtin_amdgcn_s_sleep(2);
            }
            if (l2ok)
                asm volatile("buffer_inv sc0" ::: "memory");
            __builtin_amdgcn_sched_barrier(0);
        }
    }
}

// ============================================================================
// V2: TLP variant. 512 WGs x 256 thr, 2 WGs/CU (72KB LDS each), 2 waves/SIMD.
// WG (rblk=bid&7, cblk=bid>>3 in 0..63): 64 rows x 8 cols. Weight A-operand
// uses alr&7 (rows 8-15 of each MFMA are discarded -> half M wasted, bought
// back by dual-wave latency hiding). Sync groups = 64 WGs (one XCD at bid%8),
// polled by all 64 lanes in one load. Chunked 2-deep state loads (~200 VGPR).
// Sync/coherence protocol = R11/R13 verbatim. Only launched when the runtime
// occupancy query confirms 2 blocks/CU (liveness gate).
// ============================================================================
template <bool XB>
__global__ __launch_bounds__(256, 2) void lstm_v2(
    const float* __restrict__ x, const __bf16* __restrict__ xb,
    const float* __restrict__ tseq,
    const float* __restrict__ b_i, const float* __restrict__ b_f,
    const float* __restrict__ b_c, const float* __restrict__ b_o,
    const float* __restrict__ b_e,
    const __bf16* __restrict__ GwT, const __bf16* __restrict__ WeT,
    __bf16* __restrict__ state, int* __restrict__ flags,
    float* __restrict__ out)
{
    __shared__ __align__(16) __bf16 wlds[4][8][1024];   // 64 KB
    __shared__ __align__(16) __bf16 welds[8][512];      // 8 KB -> 72 KB/WG

    const int tid = threadIdx.x;
    const int bid = blockIdx.x;
    const int rblk = bid & 7;
    const int cblk = bid >> 3;        // 0..63
    const int j0 = cblk << 3;         // 8 cols
    const int wave = tid >> 6;
    const int lane = tid & 63;
    const int alr = lane & 15;
    const int aj = alr & 7;           // weight row (broadcast pair)
    const int hq = lane >> 4;
    const int kbase = hq * 8;
    const bool jval = hq < 2;         // C rows j<8 valid

    for (int e = tid * 8; e < 4 * 8 * 1024; e += 256 * 8) {
        const int g = e >> 13;
        const int j = (e >> 10) & 7;
        const int k = e & 1023;
        *(uint4*)&wlds[g][j][SWZ(j, k)] =
            *(const uint4*)&GwT[((size_t)(g * 512 + j0 + j) << 10) + k];
    }
    for (int e = tid * 8; e < 8 * 512; e += 256 * 8) {
        const int j = e >> 9;
        const int k = e & 511;
        *(uint4*)&welds[j][SWZ(j, k)] =
            *(const uint4*)&WeT[((size_t)(j0 + j) << 9) + k];
    }
    __syncthreads();

    const int brow = rblk * 64 + wave * 16 + alr;
    const int jbase = j0 + (hq & 1) * 4;    // clamped for hq>=2 (reads safe)
    const f32x4 Bi4 = *(const f32x4*)(b_i + jbase);
    const f32x4 Bf4 = *(const f32x4*)(b_f + jbase);
    const f32x4 Bc4 = *(const f32x4*)(b_c + jbase);
    const f32x4 Bo4 = *(const f32x4*)(b_o + jbase);
    const f32x4 Be4 = *(const f32x4*)(b_e + jbase);

    const float* xrow = x + (size_t)brow * S_SZ * D_SZ;
    const __bf16* xrowb = XB ? xb + (size_t)brow * S_SZ * D_SZ : nullptr;
    const float* tsrow = tseq + (size_t)brow * S_SZ;
    const size_t hoff = (size_t)brow * H_SZ;
    float* outrow = out + (size_t)brow * S_SZ * H_SZ + jbase;

    int* gflags = flags + rblk * GRPI;
    int* myflag = gflags + cblk * 32;
    const int* pollp = gflags + lane * 32;      // 64 lanes cover 64 WGs

    int* xgrp = flags + XCCI + rblk * GRPI;
    unsigned xcc;
    asm volatile("s_getreg_b32 %0, hwreg(HW_REG_XCC_ID)" : "=s"(xcc));
    if (tid == 0)
        __hip_atomic_store(xgrp + cblk * 32, (int)xcc + 1,
                           __ATOMIC_RELAXED, __HIP_MEMORY_SCOPE_AGENT);
    int vx;
    const int* xpoll = xgrp + lane * 32;
    for (;;) {
        vx = __hip_atomic_load(xpoll, __ATOMIC_RELAXED, __HIP_MEMORY_SCOPE_AGENT);
        if (__all(vx != 0)) break;
        __builtin_amdgcn_s_sleep(1);
    }
    const bool l2ok = __all(vx == __shfl(vx, 0, 64));

    bf16x8 xbf[16];
    if constexpr (XB) {
        #pragma unroll
        for (int kk = 0; kk < 16; ++kk)
            xbf[kk] = *(const bf16x8*)(xrowb + kk * 32 + kbase);
    } else {
        #pragma unroll
        for (int kk = 0; kk < 16; ++kk) {
            f32x4 u = *(const f32x4*)(xrow + kk * 32 + kbase);
            f32x4 v = *(const f32x4*)(xrow + kk * 32 + kbase + 4);
            bf16x8 a;
            a[0] = (__bf16)u[0]; a[1] = (__bf16)u[1]; a[2] = (__bf16)u[2]; a[3] = (__bf16)u[3];
            a[4] = (__bf16)v[0]; a[5] = (__bf16)v[1]; a[6] = (__bf16)v[2]; a[7] = (__bf16)v[3];
            xbf[kk] = a;
        }
    }

    for (int t = 0; t < S_SZ; ++t) {
        const __bf16* hp = state + (size_t)(t & 1) * STATE_PAR_ELEMS;
        const __bf16* cp = hp + (size_t)H_SZ * B_SZ;
        __bf16* hnx = state + (size_t)((t + 1) & 1) * STATE_PAR_ELEMS;
        __bf16* cnx = hnx + (size_t)H_SZ * B_SZ;

        const float fa = (t + 1 < S_SZ) ? tsrow[t + 1] : 0.f;
        const __bf16* hb = hp + hoff + kbase;
        const __bf16* cb = cp + hoff + kbase;

        // chunked 2-deep state loads (low VGPR); latency hides under x@U
        HU hA[4], cA[4], hB[4], cB[4];
        LOADCH(hA, cA, 0);
        LOADCH(hB, cB, 4);

        f32x4 a0 = Bi4, a1 = Bf4, a2 = Bc4, a3 = Bo4, a4 = Be4;

        // x@U (weights from LDS, aj broadcast)
        #pragma unroll
        for (int kk = 0; kk < 16; ++kk) {
            const int k = SWZ(aj, kk * 32 + kbase);
            bf16x8 w0 = *(const bf16x8*)&wlds[0][aj][k];
            bf16x8 w1 = *(const bf16x8*)&wlds[1][aj][k];
            bf16x8 w2 = *(const bf16x8*)&wlds[2][aj][k];
            bf16x8 w3 = *(const bf16x8*)&wlds[3][aj][k];
            a0 = __builtin_amdgcn_mfma_f32_16x16x32_bf16(w0, xbf[kk], a0, 0, 0, 0);
            a1 = __builtin_amdgcn_mfma_f32_16x16x32_bf16(w1, xbf[kk], a1, 0, 0, 0);
            a2 = __builtin_amdgcn_mfma_f32_16x16x32_bf16(w2, xbf[kk], a2, 0, 0, 0);
            a3 = __builtin_amdgcn_mfma_f32_16x16x32_bf16(w3, xbf[kk], a3, 0, 0, 0);
        }

        // h@V + cf@We, chunk-pipelined
        #define CONS(hbuf, cbuf, kk0) do {                                    \
            _Pragma("unroll")                                                 \
            for (int i_ = 0; i_ < 4; ++i_) {                                  \
                const int kk_ = (kk0) + i_;                                   \
                const int k_ = SWZ(aj, 512 + kk_ * 32 + kbase);               \
                bf16x8 w0 = *(const bf16x8*)&wlds[0][aj][k_];                 \
                bf16x8 w1 = *(const bf16x8*)&wlds[1][aj][k_];                 \
                bf16x8 w2 = *(const bf16x8*)&wlds[2][aj][k_];                 \
                bf16x8 w3 = *(const bf16x8*)&wlds[3][aj][k_];                 \
                bf16x8 we = *(const bf16x8*)&welds[aj][SWZ(aj, kk_ * 32 + kbase)]; \
                a0 = __builtin_amdgcn_mfma_f32_16x16x32_bf16(w0, (hbuf)[i_].v, a0, 0, 0, 0); \
                a1 = __builtin_amdgcn_mfma_f32_16x16x32_bf16(w1, (hbuf)[i_].v, a1, 0, 0, 0); \
                a2 = __builtin_amdgcn_mfma_f32_16x16x32_bf16(w2, (hbuf)[i_].v, a2, 0, 0, 0); \
                a3 = __builtin_amdgcn_mfma_f32_16x16x32_bf16(w3, (hbuf)[i_].v, a3, 0, 0, 0); \
                a4 = __builtin_amdgcn_mfma_f32_16x16x32_bf16(we, (cbuf)[i_].v, a4, 0, 0, 0); \
            }                                                                 \
        } while (0)
        CONS(hA, cA, 0);
        LOADCH(hA, cA, 8);
        CONS(hB, cB, 4);
        LOADCH(hB, cB, 12);
        CONS(hA, cA, 8);
        CONS(hB, cB, 12);
        #undef CONS

        // x[t+1] prefetch
        const int tp = (t + 1 < S_SZ) ? t + 1 : t;
        f32x4 xf[32];
        if constexpr (XB) {
            const __bf16* xpn = xrowb + (size_t)tp * D_SZ;
            #pragma unroll
            for (int kk = 0; kk < 16; ++kk)
                xbf[kk] = *(const bf16x8*)(xpn + kk * 32 + kbase);
        } else {
            const float* xpn = xrow + (size_t)tp * D_SZ;
            #pragma unroll
            for (int kk = 0; kk < 16; ++kk) {
                xf[2 * kk]     = *(const f32x4*)(xpn + kk * 32 + kbase);
                xf[2 * kk + 1] = *(const f32x4*)(xpn + kk * 32 + kbase + 4);
            }
        }

        // elementwise + stores (only hq<2 threads own valid j rows)
        f32x4 hv4, cv4;
        union { bf16x4 v; u64 u; } ph8, pc8;
        #pragma unroll
        for (int e = 0; e < 4; ++e) {
            float it = sigmoidf_(a0[e]);
            float ft = sigmoidf_(a1[e]);
            float gt = tanhf_(a2[e]);
            float ot = sigmoidf_(a3[e]);
            float ctl = tanhf_(a4[e]);
            float cv = ft * ctl + it * gt;
            float hv = ot * tanhf_(cv);
            hv4[e] = hv; cv4[e] = cv;
            ph8.v[e] = (__bf16)hv;
            pc8.v[e] = (__bf16)(cv * fa);
        }
        if (jval) {
            __builtin_nontemporal_store(hv4, (f32x4*)(outrow + (size_t)t * H_SZ));
            if (t == S_SZ - 1) {
                float* tail = out + (size_t)B_SZ * S_SZ * H_SZ;
                *(f32x4*)(tail + hoff + jbase) = hv4;
                *(f32x4*)(tail + (size_t)B_SZ * H_SZ + hoff + jbase) = cv4;
            }
            if (l2ok) {
                *(u64*)(hnx + hoff + jbase) = ph8.u;
                *(u64*)(cnx + hoff + jbase) = pc8.u;
            } else {
                coh_store((u64*)(hnx + hoff + jbase), ph8.u);
                coh_store((u64*)(cnx + hoff + jbase), pc8.u);
            }
        }

        if constexpr (!XB) {
            #pragma unroll
            for (int kk = 0; kk < 16; ++kk) {
                f32x4 u = xf[2 * kk], v = xf[2 * kk + 1];
                bf16x8 a;
                a[0] = (__bf16)u[0]; a[1] = (__bf16)u[1]; a[2] = (__bf16)u[2]; a[3] = (__bf16)u[3];
                a[4] = (__bf16)v[0]; a[5] = (__bf16)v[1]; a[6] = (__bf16)v[2]; a[7] = (__bf16)v[3];
                xbf[kk] = a;
            }
        }

        // flag barrier: proven protocol (agent atomics both sides) + vL1 inv
        if (t < S_SZ - 1) {
            __syncthreads();
            if (tid == 0)
                __hip_atomic_store(myflag, t + 1, __ATOMIC_RELAXED,
                                   __HIP_MEMORY_SCOPE_AGENT);
            const int target = t + 1;
            for (;;) {
                int v = __hip_atomic_load(pollp, __ATOMIC_RELAXED,
                                          __HIP_MEMORY_SCOPE_AGENT);
                if (__all(v >= target)) break;
                __builtin_amdgcn_s_sleep(2);
            }
            if (l2ok)
                asm volatile("buffer_inv sc0" ::: "memory");
            __builtin_amdgcn_sched_barrier(0);
        }
    }
}

extern "C" void kernel_launch(void* const* d_in, const int* in_sizes, int n_in,
                              void* d_out, int out_size, void* d_ws, size_t ws_size,
                              hipStream_t stream) {
    const float* x  = (const float*)d_in[0];
    const float* ts = (const float*)d_in[1];
    const float* We = (const float*)d_in[2];
    const float* be = (const float*)d_in[3];
    const float* Ui = (const float*)d_in[4];
    const float* Vi = (const float*)d_in[5];
    const float* bi = (const float*)d_in[6];
    const float* Uf = (const float*)d_in[7];
    const float* Vf = (const float*)d_in[8];
    const float* bf = (const float*)d_in[9];
    const float* Uc = (const float*)d_in[10];
    const float* Vc = (const float*)d_in[11];
    const float* bc = (const float*)d_in[12];
    const float* Uo = (const float*)d_in[13];
    const float* Vo = (const float*)d_in[14];
    const float* bo = (const float*)d_in[15];

    char* ws = (char*)d_ws;
    int* flags = (int*)ws;
    __bf16* state = (__bf16*)(ws + STATE_OFF);
    __bf16* GwT = (__bf16*)(ws + GWT_OFF_BYTES);
    __bf16* WeT = (__bf16*)(ws + WET_OFF_BYTES);

    hipMemsetAsync(ws, 0, FLAGS_BYTES + 1048576, stream);
    prep_weights<<<2560, 256, 0, stream>>>(We, Ui, Vi, Uf, Vf, Uc, Vc, Uo, Vo, GwT, WeT);

    const bool xbok = ws_size >= (size_t)XB_OFF_BYTES + XB_BYTES;
    __bf16* xbp = (__bf16*)(ws + XB_OFF_BYTES);
    if (xbok)
        xcvt<<<(int)(B_SZ * S_SZ * D_SZ / 8 / 256), 256, 0, stream>>>(x, xbp);

    // Liveness gate: v2's 64-WG barrier requires all 512 WGs co-resident
    // (2 blocks/CU). Verify with the occupancy query; else run proven v1.
    int nb = 0;
    if (xbok)
        hipOccupancyMaxActiveBlocksPerMultiprocessor(
            &nb, reinterpret_cast<const void*>(&lstm_v2<true>), 256, 0);
    else
        hipOccupancyMaxActiveBlocksPerMultiprocessor(
            &nb, reinterpret_cast<const void*>(&lstm_v2<false>), 256, 0);

    if (nb >= 2) {
        if (xbok)
            lstm_v2<true><<<512, 256, 0, stream>>>(x, xbp, ts, bi, bf, bc, bo, be,
                                                   GwT, WeT, state, flags,
                                                   (float*)d_out);
        else
            lstm_v2<false><<<512, 256, 0, stream>>>(x, nullptr, ts, bi, bf, bc, bo,
                                                    be, GwT, WeT, state, flags,
                                                    (float*)d_out);
    } else {
        if (xbok)
            lstm_v1<true><<<256, 256, 0, stream>>>(x, xbp, ts, bi, bf, bc, bo, be,
                                                   GwT, WeT, state, flags,
                                                   (float*)d_out);
        else
            lstm_v1<false><<<256, 256, 0, stream>>>(x, nullptr, ts, bi, bf, bc, bo,
                                                    be, GwT, WeT, state, flags,
                                                    (float*)d_out);
    }
}